// Round 11
// baseline (258.192 us; speedup 1.0000x reference)
//
#include <hip/hip_runtime.h>
#include <math.h>

#define B 8
#define N 1024
#define L 16
#define D 256
#define H 4
#define DH 64
#define NLAYERS 2
#define V 32000

typedef __attribute__((ext_vector_type(8))) short short8;
typedef __attribute__((ext_vector_type(4))) float f32x4;

union U8 { uint4 u; short8 s; };

__device__ inline unsigned short f2bf(float x) {
    unsigned u = __float_as_uint(x);
    u = (u + 0x7fff + ((u >> 16) & 1)) >> 16;  // RNE
    return (unsigned short)u;
}
__device__ inline float bf2f(unsigned short x) {
    return __uint_as_float(((unsigned)x) << 16);
}

// -------- layouts --------
// h_sw  [b][n>>4][d>>5][n&15][d&31]  bf16 (A of k_wh1; written by attn_ln l0)
// WT_sw [lh][d>>5][dh][d&31]         bf16 (B of Wh GEMMs)
// WhT   [bh][m>>5][dh][m&31]         bf16 (B of attn)
// pack  [b][n][m/64]                 u64 adjacency (+self-loop)
// emb_bf[V][D]                       bf16 emb copy

#define PACK_BLK 2048
#define WT_BLK   (NLAYERS * H * 4)
#define EMB_BLK  500
#define PRE1_GRID (PACK_BLK + WT_BLK + EMB_BLK + 1)

// ---- pre1: packadj + WT transpose + emb->bf16 + len ----
__global__ __launch_bounds__(256) void k_pre1(const int* __restrict__ adj,
                                              const float* __restrict__ W,
                                              const int* __restrict__ len,
                                              const float* __restrict__ emb,
                                              unsigned long long* __restrict__ pack,
                                              unsigned short* __restrict__ WT_sw,
                                              unsigned short* __restrict__ emb_bf,
                                              float* __restrict__ out_len) {
    int bid = blockIdx.x;
    int t = threadIdx.x;
    if (bid < PACK_BLK) {
        int row = bid * 4 + (t >> 6);  // bn
        int lane = t & 63;
        int n = row & (N - 1);
        const int* arow = adj + (long)row * N;
        unsigned long long* prow = pack + (size_t)row * 16;
        int g16 = lane & 15;
#pragma unroll
        for (int it = 0; it < 4; ++it) {
            int m0 = it * 256 + lane * 4;
            int4 a = *(const int4*)(arow + m0);
            unsigned nib = (unsigned)((a.x != 0) || (m0 == n))
                         | ((unsigned)((a.y != 0) || (m0 + 1 == n)) << 1)
                         | ((unsigned)((a.z != 0) || (m0 + 2 == n)) << 2)
                         | ((unsigned)((a.w != 0) || (m0 + 3 == n)) << 3);
            unsigned long long v = (unsigned long long)nib << (g16 * 4);
            v |= __shfl_xor(v, 1, 64);
            v |= __shfl_xor(v, 2, 64);
            v |= __shfl_xor(v, 4, 64);
            v |= __shfl_xor(v, 8, 64);
            if (g16 == 0) prow[it * 4 + (lane >> 4)] = v;
        }
    } else if (bid < PACK_BLK + WT_BLK) {
        int idx = bid - PACK_BLK;
        int lh = idx >> 2, q = idx & 3;
        const float* Wl = W + (size_t)lh * D * DH;
        int dh = t & 63;
        int d0 = q * 64 + (t >> 6) * 16;
#pragma unroll
        for (int i = 0; i < 16; ++i) {
            int d = d0 + i;
            WT_sw[(((size_t)lh * 8 + (d >> 5)) * 64 + dh) * 32 + (d & 31)] = f2bf(Wl[(size_t)d * DH + dh]);
        }
    } else if (bid < PACK_BLK + WT_BLK + EMB_BLK) {
        size_t base = (size_t)(bid - PACK_BLK - WT_BLK) * 16384 + (size_t)t * 4;
#pragma unroll
        for (int i = 0; i < 16; ++i) {
            float4 v = *(const float4*)&emb[base + (size_t)i * 1024];
            ushort4 o;
            o.x = f2bf(v.x); o.y = f2bf(v.y); o.z = f2bf(v.z); o.w = f2bf(v.w);
            *(ushort4*)&emb_bf[base + (size_t)i * 1024] = o;
        }
    } else {
        if (t < B) out_len[t] = (float)len[t];
    }
}

// ---- shared epilogue helper: WhT stage + srcv/dstv (device inline) ----
__device__ inline void wh_epilogue(float (*wtmp)[16][68], const f32x4* acc,
                                   const float* asrc_l, const float* adst_l,
                                   unsigned short* WhT, float* srcv, float* dstv,
                                   int b, int n0, int tid) {
    int hh = tid >> 6, lane = tid & 63;
    int rowLane = lane & 15, quad = lane >> 4;
    int bh = b * H + hh;
    // srcv/dstv straight from registers (full-K accumulators)
    float as[4], ad[4];
#pragma unroll
    for (int c = 0; c < 4; ++c) {
        as[c] = asrc_l[hh * DH + c * 16 + rowLane];
        ad[c] = adst_l[hh * DH + c * 16 + rowLane];
    }
#pragma unroll
    for (int rr = 0; rr < 4; ++rr) {
        float sp = acc[0][rr] * as[0] + acc[1][rr] * as[1] + acc[2][rr] * as[2] + acc[3][rr] * as[3];
        float dp = acc[0][rr] * ad[0] + acc[1][rr] * ad[1] + acc[2][rr] * ad[2] + acc[3][rr] * ad[3];
#pragma unroll
        for (int off = 8; off; off >>= 1) {
            sp += __shfl_xor(sp, off, 16);
            dp += __shfl_xor(dp, off, 16);
        }
        if (rowLane == 0) {
            srcv[(size_t)bh * N + n0 + quad * 4 + rr] = sp;
            dstv[(size_t)bh * N + n0 + quad * 4 + rr] = dp;
        }
    }
    // stage + coalesced bf16 WhT write
#pragma unroll
    for (int c = 0; c < 4; ++c)
#pragma unroll
        for (int rr = 0; rr < 4; ++rr)
            wtmp[hh][quad * 4 + rr][c * 16 + rowLane] = acc[c][rr];
    __syncthreads();
    int hh2 = tid >> 6, dh = tid & 63;
    int bh2 = b * H + hh2;
#pragma unroll
    for (int j4 = 0; j4 < 4; ++j4) {
        ushort4 o;
        o.x = f2bf(wtmp[hh2][j4 * 4 + 0][dh]);
        o.y = f2bf(wtmp[hh2][j4 * 4 + 1][dh]);
        o.z = f2bf(wtmp[hh2][j4 * 4 + 2][dh]);
        o.w = f2bf(wtmp[hh2][j4 * 4 + 3][dh]);
        *(ushort4*)&WhT[(((size_t)bh2 * 32 + (n0 >> 5)) * 64 + dh) * 32 + (n0 & 31) + j4 * 4] = o;
    }
}

// ---- k_feat_wh: nodefeat + layer-0 Wh. Block = (b, 16-row tile); wave = head ----
__global__ __launch_bounds__(256) void k_feat_wh(const int* __restrict__ nodes,
                                                 const unsigned short* __restrict__ emb_bf,
                                                 const unsigned short* __restrict__ WT_l,
                                                 const float* __restrict__ asrc_l,
                                                 const float* __restrict__ adst_l,
                                                 float* __restrict__ h,
                                                 unsigned short* __restrict__ WhT,
                                                 float* __restrict__ srcv,
                                                 float* __restrict__ dstv) {
    __shared__ int ndl[256];
    __shared__ unsigned short a_lds[8][16][40];  // pad 40: b128 reads spread banks
    __shared__ float wtmp[4][16][68];
    int bt = blockIdx.x;
    int b = bt >> 6, nt = bt & 63, n0 = nt * 16;
    int tid = threadIdx.x;
    ndl[tid] = nodes[((size_t)(b * N + n0)) * L + tid];
    __syncthreads();
    int r = tid >> 4, g = tid & 15;
    float s[16] = {};
#pragma unroll
    for (int l = 0; l < L; ++l) {
        int tok = ndl[r * 16 + l];
        short8 v0 = *(const short8*)&emb_bf[(size_t)tok * D + g * 16];
        short8 v1 = *(const short8*)&emb_bf[(size_t)tok * D + g * 16 + 8];
#pragma unroll
        for (int k = 0; k < 8; ++k) {
            s[k] += bf2f((unsigned short)v0[k]);
            s[8 + k] += bf2f((unsigned short)v1[k]);
        }
    }
#pragma unroll
    for (int k = 0; k < 16; ++k) s[k] *= (1.0f / L);
    float* hrow = h + ((size_t)(b * N + n0 + r)) * D + g * 16;
    *(float4*)(hrow + 0) = make_float4(s[0], s[1], s[2], s[3]);
    *(float4*)(hrow + 4) = make_float4(s[4], s[5], s[6], s[7]);
    *(float4*)(hrow + 8) = make_float4(s[8], s[9], s[10], s[11]);
    *(float4*)(hrow + 12) = make_float4(s[12], s[13], s[14], s[15]);
    unsigned short ob[16];
#pragma unroll
    for (int k = 0; k < 16; ++k) ob[k] = f2bf(s[k]);
    *(short8*)&a_lds[g >> 1][r][(g & 1) * 16] = *(short8*)&ob[0];
    *(short8*)&a_lds[g >> 1][r][(g & 1) * 16 + 8] = *(short8*)&ob[8];
    __syncthreads();
    int hh = tid >> 6, lane = tid & 63;
    int rowLane = lane & 15, quad = lane >> 4;
    const unsigned short* bbase = WT_l + ((size_t)hh * 8) * 2048 + rowLane * 32 + quad * 8;
    f32x4 acc[4] = {};
#pragma unroll
    for (int kc = 0; kc < 8; ++kc) {
        short8 af = *(const short8*)&a_lds[kc][rowLane][quad * 8];
#pragma unroll
        for (int c = 0; c < 4; ++c)
            acc[c] = __builtin_amdgcn_mfma_f32_16x16x32_bf16(af, *(const short8*)(bbase + kc * 2048 + c * 512), acc[c], 0, 0, 0);
    }
    wh_epilogue(wtmp, acc, asrc_l, adst_l, WhT, srcv, dstv, b, n0, tid);
}

// ---- k_wh1: layer-1 Wh from h_sw. Block = (b, 16-row tile); wave = head ----
__global__ __launch_bounds__(256) void k_wh1(const unsigned short* __restrict__ h_sw,
                                             const unsigned short* __restrict__ WT_l,
                                             const float* __restrict__ asrc_l,
                                             const float* __restrict__ adst_l,
                                             unsigned short* __restrict__ WhT,
                                             float* __restrict__ srcv,
                                             float* __restrict__ dstv) {
    __shared__ float wtmp[4][16][68];
    int bt = blockIdx.x;
    int b = bt >> 6, nt = bt & 63, n0 = nt * 16;
    int tid = threadIdx.x;
    int hh = tid >> 6, lane = tid & 63;
    int rowLane = lane & 15, quad = lane >> 4;
    const unsigned short* abase = h_sw + (((size_t)b * 64 + nt) * 8) * 512 + rowLane * 32 + quad * 8;
    const unsigned short* bbase = WT_l + ((size_t)hh * 8) * 2048 + rowLane * 32 + quad * 8;
    f32x4 acc[4] = {};
#pragma unroll
    for (int kc = 0; kc < 8; ++kc) {
        short8 af = *(const short8*)(abase + kc * 512);
#pragma unroll
        for (int c = 0; c < 4; ++c)
            acc[c] = __builtin_amdgcn_mfma_f32_16x16x32_bf16(af, *(const short8*)(bbase + kc * 2048 + c * 512), acc[c], 0, 0, 0);
    }
    wh_epilogue(wtmp, acc, asrc_l, adst_l, WhT, srcv, dstv, b, n0, tid);
}

// ---- k_attn_ln: attn (wave = head, full m) + in-block LN ----
__global__ __launch_bounds__(256) void k_attn_ln(const unsigned long long* __restrict__ pack,
                                                 const float* __restrict__ srcv,
                                                 const float* __restrict__ dstv,
                                                 const unsigned short* __restrict__ WhT,
                                                 const float* __restrict__ h_in,
                                                 const float* __restrict__ scale_l,
                                                 const float* __restrict__ bias_l,
                                                 float* __restrict__ out_f32,
                                                 unsigned short* __restrict__ h_sw_out,
                                                 int has_next) {
    __shared__ float dsts[4][1024];
    __shared__ float xbuf[16][272];   // pad 272: quad rows land on distinct banks
    int bt = blockIdx.x;
    int b = bt >> 6, nt = bt & 63, n0 = nt * 16;
    int tid = threadIdx.x;
    int hh = tid >> 6, lane = tid & 63;
    int rowLane = lane & 15, quad = lane >> 4;
    int bh = b * H + hh;
    int n = n0 + rowLane;

    // stage own head's full dst row (wave-local)
#pragma unroll
    for (int i = 0; i < 4; ++i) {
        float4 v = *(const float4*)(dstv + (size_t)bh * N + i * 256 + lane * 4);
        *(float4*)&dsts[hh][i * 256 + lane * 4] = v;
    }
    const uint4* pbp = (const uint4*)(pack + ((size_t)(b * N + n)) * 16);
    uint4 pw[8];
#pragma unroll
    for (int i = 0; i < 8; ++i) pw[i] = pbp[i];
    float src = srcv[(size_t)bh * N + n];
    float mx = src > 0.f ? src : 0.2f * src;   // local stable shift (exact: h' invariant)

    const unsigned short* wbase = WhT + (size_t)bh * 65536 + rowLane * 32 + quad * 8;
    f32x4 acc[4] = {};
    float sum0 = 0.f, sum1 = 0.f;
#pragma unroll
    for (int t2 = 0; t2 < 32; ++t2) {
        uint4 q = pw[t2 >> 2];
        unsigned w32 = (t2 & 3) == 0 ? q.x : (t2 & 3) == 1 ? q.y : (t2 & 3) == 2 ? q.z : q.w;
        unsigned bits = (w32 >> (quad * 8)) & 0xffu;
        float4 d0 = *(const float4*)&dsts[hh][t2 * 32 + quad * 8];
        float4 d1 = *(const float4*)&dsts[hh][t2 * 32 + quad * 8 + 4];
        float dd[8] = {d0.x, d0.y, d0.z, d0.w, d1.x, d1.y, d1.z, d1.w};
        unsigned pk[4];
#pragma unroll
        for (int j2 = 0; j2 < 4; ++j2) {
            float ea = src + dd[2 * j2];
            float eb = src + dd[2 * j2 + 1];
            ea = ea > 0.f ? ea : 0.2f * ea;
            eb = eb > 0.f ? eb : 0.2f * eb;
            float pa = ((bits >> (2 * j2)) & 1) ? __expf(ea - mx) : 0.f;
            float pb = ((bits >> (2 * j2 + 1)) & 1) ? __expf(eb - mx) : 0.f;
            sum0 += pa; sum1 += pb;
            pk[j2] = (__float_as_uint(pb) & 0xffff0000u) | (__float_as_uint(pa) >> 16);
        }
        U8 u; u.u = make_uint4(pk[0], pk[1], pk[2], pk[3]);
        short8 af = u.s;
        const unsigned short* tb = wbase + (size_t)t2 * 2048;
        acc[0] = __builtin_amdgcn_mfma_f32_16x16x32_bf16(af, *(const short8*)(tb + 0 * 512), acc[0], 0, 0, 0);
        acc[1] = __builtin_amdgcn_mfma_f32_16x16x32_bf16(af, *(const short8*)(tb + 1 * 512), acc[1], 0, 0, 0);
        acc[2] = __builtin_amdgcn_mfma_f32_16x16x32_bf16(af, *(const short8*)(tb + 2 * 512), acc[2], 0, 0, 0);
        acc[3] = __builtin_amdgcn_mfma_f32_16x16x32_bf16(af, *(const short8*)(tb + 3 * 512), acc[3], 0, 0, 0);
    }
    float sum = sum0 + sum1;
    sum += __shfl_xor(sum, 16, 64);
    sum += __shfl_xor(sum, 32, 64);   // S complete per rowLane (full m in-wave)
#pragma unroll
    for (int rr = 0; rr < 4; ++rr) {
        float Sr = __shfl(sum, quad * 4 + rr, 16);
        float inv = 1.0f / Sr;
#pragma unroll
        for (int c = 0; c < 4; ++c)
            xbuf[quad * 4 + rr][hh * 64 + c * 16 + rowLane] = acc[c][rr] * inv;
    }
    __syncthreads();
    // ---- LN over 256 channels per row ----
    int r = tid >> 4, g = tid & 15;
    size_t bn = (size_t)b * N + n0 + r;
    float x[16];
    const float* hr = h_in + bn * D + g * 16;
#pragma unroll
    for (int i4 = 0; i4 < 4; ++i4) {
        float4 xv = *(const float4*)&xbuf[r][g * 16 + i4 * 4];
        float4 hv = *(const float4*)(hr + i4 * 4);
        x[i4 * 4 + 0] = xv.x + hv.x;
        x[i4 * 4 + 1] = xv.y + hv.y;
        x[i4 * 4 + 2] = xv.z + hv.z;
        x[i4 * 4 + 3] = xv.w + hv.w;
    }
    float s1 = 0.f, s2 = 0.f;
#pragma unroll
    for (int i = 0; i < 16; ++i) { s1 += x[i]; s2 += x[i] * x[i]; }
#pragma unroll
    for (int off = 8; off; off >>= 1) {
        s1 += __shfl_xor(s1, off, 16);
        s2 += __shfl_xor(s2, off, 16);
    }
    float mu = s1 * (1.0f / D);
    float var = s2 * (1.0f / D) - mu * mu;
    float rstd = rsqrtf(var + 1e-5f);
    const float* sc = scale_l + g * 16;
    const float* bi = bias_l + g * 16;
    float y[16];
#pragma unroll
    for (int i = 0; i < 16; ++i) y[i] = (x[i] - mu) * rstd * sc[i] + bi[i];
    float* orow = out_f32 + bn * D + g * 16;
    *(float4*)(orow + 0) = make_float4(y[0], y[1], y[2], y[3]);
    *(float4*)(orow + 4) = make_float4(y[4], y[5], y[6], y[7]);
    *(float4*)(orow + 8) = make_float4(y[8], y[9], y[10], y[11]);
    *(float4*)(orow + 12) = make_float4(y[12], y[13], y[14], y[15]);
    if (has_next) {
        unsigned short ob[16];
#pragma unroll
        for (int i = 0; i < 16; ++i) ob[i] = f2bf(y[i]);
        unsigned short* hswp = h_sw_out + (((size_t)b * 64 + nt) * 8 + (g >> 1)) * 512 + r * 32 + (g & 1) * 16;
        *(short8*)(hswp + 0) = *(short8*)&ob[0];
        *(short8*)(hswp + 8) = *(short8*)&ob[8];
    }
}

extern "C" void kernel_launch(void* const* d_in, const int* in_sizes, int n_in,
                              void* d_out, int out_size, void* d_ws, size_t ws_size,
                              hipStream_t stream) {
    const int* cfg_adj = (const int*)d_in[0];
    const int* cfg_nodes = (const int*)d_in[1];
    const int* cfg_len = (const int*)d_in[2];
    const float* emb = (const float*)d_in[3];
    const float* W = (const float*)d_in[4];
    const float* a_src = (const float*)d_in[5];
    const float* a_dst = (const float*)d_in[6];
    const float* ln_scale = (const float*)d_in[7];
    const float* ln_bias = (const float*)d_in[8];
    float* out = (float*)d_out;
    float* ws = (float*)d_ws;

    float* h = ws;
    float* srcv = h + (size_t)B * N * D;
    float* dstv = srcv + (size_t)B * H * N;
    unsigned short* h_sw = (unsigned short*)(dstv + (size_t)B * H * N);
    unsigned short* WhT = h_sw + (size_t)B * N * D;
    unsigned short* WT_sw = WhT + (size_t)B * H * DH * N;
    unsigned short* emb_bf = WT_sw + (size_t)NLAYERS * H * DH * D;
    unsigned long long* pack = (unsigned long long*)(emb_bf + (size_t)V * D);

    k_pre1<<<PRE1_GRID, 256, 0, stream>>>(cfg_adj, W, cfg_len, emb, pack, WT_sw,
                                          emb_bf, out + (size_t)B * N * D);
    k_feat_wh<<<B * 64, 256, 0, stream>>>(cfg_nodes, emb_bf, WT_sw,
                                          a_src, a_dst, h, WhT, srcv, dstv);
    k_attn_ln<<<B * 64, 256, 0, stream>>>(pack, srcv, dstv, WhT, h,
                                          ln_scale, ln_bias, h, h_sw, 1);
    k_wh1<<<B * 64, 256, 0, stream>>>(h_sw, WT_sw + (size_t)H * 8 * 2048,
                                      a_src + (size_t)H * DH, a_dst + (size_t)H * DH,
                                      WhT, srcv, dstv);
    k_attn_ln<<<B * 64, 256, 0, stream>>>(pack, srcv, dstv, WhT, h,
                                          ln_scale + D, ln_bias + D, out, (unsigned short*)0, 0);
}

// Round 12
// 202.475 us; speedup vs baseline: 1.2752x; 1.2752x over previous
//
#include <hip/hip_runtime.h>
#include <math.h>

#define B 8
#define N 1024
#define L 16
#define D 256
#define H 4
#define DH 64
#define NLAYERS 2
#define V 32000

typedef __attribute__((ext_vector_type(8))) short short8;
typedef __attribute__((ext_vector_type(4))) float f32x4;

union U8 { uint4 u; short8 s; };

__device__ inline unsigned short f2bf(float x) {
    unsigned u = __float_as_uint(x);
    u = (u + 0x7fff + ((u >> 16) & 1)) >> 16;  // RNE
    return (unsigned short)u;
}
__device__ inline float bf2f(unsigned short x) {
    return __uint_as_float(((unsigned)x) << 16);
}

// -------- swizzled layouts --------
// h_sw  [b][n>>4][d>>5][n&15][d&31]    bf16  (A-operand of k_wh)
// WT_sw [lh][d>>5][dh][d&31]           bf16  (B-operand of k_wh)
// WhT_sw[bh][m>>5][dh][m&31]           bf16  (B-operand of k_attn; m = source node)
// pack  [b][n][m/64]                   u64 adjacency bitmask (+self-loop)
// emb_bf[V][D]                         bf16 copy of emb

#define PACK_BLK 2048
#define WT_BLK   (NLAYERS * H * 4)   // 32
#define EMB_BLK  500                 // V*D/16384 exactly
#define PRE1_GRID (PACK_BLK + WT_BLK + EMB_BLK + 1)

// ---- pre1: packadj (int4 + nibble-shuffle) + WT transpose + emb->bf16 + len ----
__global__ __launch_bounds__(256) void k_pre1(const int* __restrict__ adj,
                                              const float* __restrict__ W,
                                              const int* __restrict__ len,
                                              const float* __restrict__ emb,
                                              unsigned long long* __restrict__ pack,
                                              unsigned short* __restrict__ WT_sw,
                                              unsigned short* __restrict__ emb_bf,
                                              float* __restrict__ out_len) {
    int bid = blockIdx.x;
    int t = threadIdx.x;
    if (bid < PACK_BLK) {
        int row = bid * 4 + (t >> 6);  // bn
        int lane = t & 63;
        int n = row & (N - 1);
        const int* arow = adj + (long)row * N;
        unsigned long long* prow = pack + (size_t)row * 16;
        int g16 = lane & 15;
#pragma unroll
        for (int it = 0; it < 4; ++it) {
            int m0 = it * 256 + lane * 4;
            int4 a = *(const int4*)(arow + m0);
            unsigned nib = (unsigned)((a.x != 0) || (m0 == n))
                         | ((unsigned)((a.y != 0) || (m0 + 1 == n)) << 1)
                         | ((unsigned)((a.z != 0) || (m0 + 2 == n)) << 2)
                         | ((unsigned)((a.w != 0) || (m0 + 3 == n)) << 3);
            unsigned long long v = (unsigned long long)nib << (g16 * 4);
            // OR-reduce within each 16-lane group (offsets 1/2/4/8 stay in-group)
            v |= __shfl_xor(v, 1, 64);
            v |= __shfl_xor(v, 2, 64);
            v |= __shfl_xor(v, 4, 64);
            v |= __shfl_xor(v, 8, 64);
            if (g16 == 0) prow[it * 4 + (lane >> 4)] = v;
        }
    } else if (bid < PACK_BLK + WT_BLK) {
        int idx = bid - PACK_BLK;
        int lh = idx >> 2, q = idx & 3;
        const float* Wl = W + (size_t)lh * D * DH;
        int dh = t & 63;
        int d0 = q * 64 + (t >> 6) * 16;
#pragma unroll
        for (int i = 0; i < 16; ++i) {
            int d = d0 + i;
            WT_sw[(((size_t)lh * 8 + (d >> 5)) * 64 + dh) * 32 + (d & 31)] = f2bf(Wl[(size_t)d * DH + dh]);
        }
    } else if (bid < PACK_BLK + WT_BLK + EMB_BLK) {
        // coalesced: iteration i covers 1024 consecutive floats, lane t gets 4
        size_t base = (size_t)(bid - PACK_BLK - WT_BLK) * 16384 + (size_t)t * 4;
#pragma unroll
        for (int i = 0; i < 16; ++i) {
            float4 v = *(const float4*)&emb[base + (size_t)i * 1024];
            ushort4 o;
            o.x = f2bf(v.x); o.y = f2bf(v.y); o.z = f2bf(v.z); o.w = f2bf(v.w);
            *(ushort4*)&emb_bf[base + (size_t)i * 1024] = o;
        }
    } else {
        if (t < B) out_len[t] = (float)len[t];
    }
}

// ---- nodefeat: mean of bf16 token embeddings -> h fp32 + h_sw bf16 ----
// 8 rows/block; 32 lanes per row, each lane covers 8 consecutive d.
__global__ __launch_bounds__(256) void k_nodefeat(const int* __restrict__ nodes,
                                                  const unsigned short* __restrict__ emb_bf,
                                                  float* __restrict__ h,
                                                  unsigned short* __restrict__ h_sw) {
    int row = blockIdx.x * 8 + (threadIdx.x >> 5);  // bn
    int lane32 = threadIdx.x & 31;
    int d8 = lane32 * 8;
    const int* np = nodes + row * L;
    float s[8] = {};
#pragma unroll
    for (int l = 0; l < L; ++l) {
        short8 v = *(const short8*)&emb_bf[(size_t)np[l] * D + d8];
#pragma unroll
        for (int k = 0; k < 8; ++k) s[k] += bf2f((unsigned short)v[k]);
    }
#pragma unroll
    for (int k = 0; k < 8; ++k) s[k] *= (1.0f / L);
    *(float4*)&h[(size_t)row * D + d8] = make_float4(s[0], s[1], s[2], s[3]);
    *(float4*)&h[(size_t)row * D + d8 + 4] = make_float4(s[4], s[5], s[6], s[7]);
    int b = row >> 10, n = row & 1023;
    unsigned short o[8];
#pragma unroll
    for (int k = 0; k < 8; ++k) o[k] = f2bf(s[k]);
    *(short8*)&h_sw[(((size_t)b * 64 + (n >> 4)) * 8 + (d8 >> 5)) * 512 + (n & 15) * 32 + (d8 & 31)] =
        *(short8*)o;
}

// ---- k_wh: WhT_sw = (h @ W)^T via MFMA; epilogue computes srcv/dstv = Wh·a ----
__global__ __launch_bounds__(256) void k_wh(const unsigned short* __restrict__ h_sw,
                                            const unsigned short* __restrict__ WT_l,
                                            const float* __restrict__ asrc_l,
                                            const float* __restrict__ adst_l,
                                            unsigned short* __restrict__ WhT,
                                            float* __restrict__ srcv,
                                            float* __restrict__ dstv) {
    __shared__ float red[4][16][68];
    int bt = blockIdx.x;   // b*64 + nt
    int hh = blockIdx.y;
    int b = bt >> 6;
    int nt = bt & 63;
    int n0 = nt * 16;
    int tid = threadIdx.x;
    int w = tid >> 6, lane = tid & 63;
    int rowLane = lane & 15, quad = lane >> 4;
    int bh = b * H + hh;
    const unsigned short* abase = h_sw + (((size_t)b * 64 + nt) * 8) * 512 + rowLane * 32 + quad * 8;
    const unsigned short* bbase = WT_l + ((size_t)hh * 8) * 2048 + rowLane * 32 + quad * 8;
    f32x4 acc[4] = {};
#pragma unroll
    for (int kk = 0; kk < 2; ++kk) {
        int kc = w * 2 + kk;
        short8 af = *(const short8*)(abase + kc * 512);
#pragma unroll
        for (int c = 0; c < 4; ++c) {
            short8 bf = *(const short8*)(bbase + kc * 2048 + c * 512);
            acc[c] = __builtin_amdgcn_mfma_f32_16x16x32_bf16(af, bf, acc[c], 0, 0, 0);
        }
    }
#pragma unroll
    for (int c = 0; c < 4; ++c)
#pragma unroll
        for (int r = 0; r < 4; ++r)
            red[w][quad * 4 + r][c * 16 + rowLane] = acc[c][r];
    __syncthreads();
    int dh = tid >> 2, j4 = tid & 3;
    float v[4];
#pragma unroll
    for (int i = 0; i < 4; ++i)
        v[i] = red[0][j4 * 4 + i][dh] + red[1][j4 * 4 + i][dh] + red[2][j4 * 4 + i][dh] + red[3][j4 * 4 + i][dh];
    ushort4 o;
    o.x = f2bf(v[0]); o.y = f2bf(v[1]); o.z = f2bf(v[2]); o.w = f2bf(v[3]);
    *(ushort4*)&WhT[(((size_t)bh * 32 + (n0 >> 5)) * 64 + dh) * 32 + (n0 & 31) + j4 * 4] = o;
    // ---- srcv/dstv = Wh·a (reuse red as ps[16][68] / pd[16][68]) ----
    float as = asrc_l[hh * DH + dh];
    float ad = adst_l[hh * DH + dh];
    float* ps = &red[0][0][0];
    float* pd = ps + 16 * 68;
    __syncthreads();   // red reads done
#pragma unroll
    for (int i = 0; i < 4; ++i) {
        ps[(j4 * 4 + i) * 68 + dh] = v[i] * as;
        pd[(j4 * 4 + i) * 68 + dh] = v[i] * ad;
    }
    __syncthreads();
    int nl = tid >> 4, g = tid & 15;
    float4 s4 = *(float4*)&ps[nl * 68 + g * 4];
    float4 t4 = *(float4*)&pd[nl * 68 + g * 4];
    float s1 = s4.x + s4.y + s4.z + s4.w;
    float d1 = t4.x + t4.y + t4.z + t4.w;
#pragma unroll
    for (int off = 8; off; off >>= 1) {
        s1 += __shfl_xor(s1, off, 16);
        d1 += __shfl_xor(d1, off, 16);
    }
    if (g == 0) {
        srcv[bh * N + n0 + nl] = s1;
        dstv[bh * N + n0 + nl] = d1;
    }
}

// ---- k_attn: alpha@Wh, deferred normalization, local shift mx=lrelu(src).
// Block = (bh, 16-row n-tile). Wave w owns m-slab [w*256,(w+1)*256). ----
__global__ __launch_bounds__(256) void k_attn(const unsigned long long* __restrict__ pack,
                                              const float* __restrict__ srcv,
                                              const float* __restrict__ dstv,
                                              const unsigned short* __restrict__ WhT,
                                              float* __restrict__ hp) {
    __shared__ float red[4][16][68];     // first 1024 floats alias dsts[4][256]
    __shared__ float ssum[4][16];
    float* dsts = &red[0][0][0];

    int tid = threadIdx.x;
    int bt = blockIdx.x;
    int bh = bt >> 6;
    int n0 = (bt & 63) * 16;
    int b = bh >> 2;
    int w = tid >> 6, lane = tid & 63;
    int rowLane = lane & 15, quad = lane >> 4;
    int n = n0 + rowLane;

    // stage own wave's dst slab (wave-local; in-wave lgkmcnt ordering suffices)
    {
        float4 v = *(const float4*)(dstv + bh * N + w * 256 + lane * 4);
        *(float4*)(dsts + w * 256 + lane * 4) = v;
    }
    const uint4* pbp = (const uint4*)((const unsigned char*)(pack + ((size_t)(b * N + n)) * 16) + w * 32);
    uint4 pbv0 = pbp[0];
    uint4 pbv1 = pbp[1];
    float src = srcv[bh * N + n];
    float mx = src > 0.f ? src : 0.2f * src;   // local stable shift

    unsigned words[8] = {pbv0.x, pbv0.y, pbv0.z, pbv0.w, pbv1.x, pbv1.y, pbv1.z, pbv1.w};
    const unsigned short* wbase = WhT + ((size_t)bh * 32) * 2048 + rowLane * 32 + quad * 8;
    f32x4 acc[4] = {};
    float sum0 = 0.f, sum1 = 0.f;
#pragma unroll
    for (int t2 = 0; t2 < 8; ++t2) {
        unsigned bits = (words[t2] >> (quad * 8)) & 0xffu;
        float4 d0 = *(const float4*)(dsts + w * 256 + t2 * 32 + quad * 8);
        float4 d1 = *(const float4*)(dsts + w * 256 + t2 * 32 + quad * 8 + 4);
        float dd[8] = {d0.x, d0.y, d0.z, d0.w, d1.x, d1.y, d1.z, d1.w};
        unsigned pk[4];
#pragma unroll
        for (int j2 = 0; j2 < 4; ++j2) {
            float ea = src + dd[2 * j2];
            float eb = src + dd[2 * j2 + 1];
            ea = ea > 0.f ? ea : 0.2f * ea;
            eb = eb > 0.f ? eb : 0.2f * eb;
            float pa = ((bits >> (2 * j2)) & 1) ? __expf(ea - mx) : 0.f;
            float pb = ((bits >> (2 * j2 + 1)) & 1) ? __expf(eb - mx) : 0.f;
            sum0 += pa; sum1 += pb;
            // truncating bf16 pack (p >= 0; normalization absorbs <=0.4% bias)
            pk[j2] = (__float_as_uint(pb) & 0xffff0000u) | (__float_as_uint(pa) >> 16);
        }
        U8 u; u.u = make_uint4(pk[0], pk[1], pk[2], pk[3]);
        short8 af = u.s;
        const unsigned short* tb = wbase + (size_t)(w * 8 + t2) * 2048;
        acc[0] = __builtin_amdgcn_mfma_f32_16x16x32_bf16(af, *(const short8*)(tb + 0 * 512), acc[0], 0, 0, 0);
        acc[1] = __builtin_amdgcn_mfma_f32_16x16x32_bf16(af, *(const short8*)(tb + 1 * 512), acc[1], 0, 0, 0);
        acc[2] = __builtin_amdgcn_mfma_f32_16x16x32_bf16(af, *(const short8*)(tb + 2 * 512), acc[2], 0, 0, 0);
        acc[3] = __builtin_amdgcn_mfma_f32_16x16x32_bf16(af, *(const short8*)(tb + 3 * 512), acc[3], 0, 0, 0);
    }
    float sum = sum0 + sum1;
    sum += __shfl_xor(sum, 16, 64);
    sum += __shfl_xor(sum, 32, 64);
    if (quad == 0) ssum[w][rowLane] = sum;
    __syncthreads();  // ssum visible; dsts reads done -> red may overwrite
#pragma unroll
    for (int c = 0; c < 4; ++c)
#pragma unroll
        for (int r = 0; r < 4; ++r)
            red[w][quad * 4 + r][c * 16 + rowLane] = acc[c][r];
    __syncthreads();
    int row = tid >> 4, col4 = (tid & 15) * 4;
    float4 s = make_float4(0.f, 0.f, 0.f, 0.f);
#pragma unroll
    for (int ww = 0; ww < 4; ++ww) {
        float4 v = *(const float4*)&red[ww][row][col4];
        s.x += v.x; s.y += v.y; s.z += v.z; s.w += v.w;
    }
    float invr = 1.0f / (ssum[0][row] + ssum[1][row] + ssum[2][row] + ssum[3][row]);
    s.x *= invr; s.y *= invr; s.z *= invr; s.w *= invr;
    *(float4*)&hp[((size_t)bh * N + n0 + row) * DH + col4] = s;
}

// ---- k_ln: LN(h + concat(hp)); emits swizzled bf16 for next layer ----
__global__ __launch_bounds__(256) void k_ln(const float* __restrict__ h,
                                            const float* __restrict__ hp,
                                            const float* __restrict__ scale,
                                            const float* __restrict__ bias,
                                            float* __restrict__ out,
                                            unsigned short* __restrict__ h_sw,
                                            int layer, int has_next) {
    __shared__ float red[8];
    int bn = blockIdx.x;
    int b = bn >> 10, n = bn & 1023;
    int c = threadIdx.x;
    int hh = c >> 6, k = c & 63;
    float x = h[(size_t)bn * D + c] + hp[((size_t)(b * H + hh) * N + n) * DH + k];
    float s = x, s2 = x * x;
#pragma unroll
    for (int off = 32; off; off >>= 1) {
        s += __shfl_xor(s, off, 64);
        s2 += __shfl_xor(s2, off, 64);
    }
    int w = c >> 6, lane = c & 63;
    if (lane == 0) { red[w] = s; red[4 + w] = s2; }
    __syncthreads();
    s = red[0] + red[1] + red[2] + red[3];
    s2 = red[4] + red[5] + red[6] + red[7];
    float mu = s * (1.0f / D);
    float var = s2 * (1.0f / D) - mu * mu;
    float r = rsqrtf(var + 1e-5f);
    float y = (x - mu) * r * scale[layer * D + c] + bias[layer * D + c];
    out[(size_t)bn * D + c] = y;
    if (has_next)
        h_sw[(((size_t)b * 64 + (n >> 4)) * 8 + (c >> 5)) * 512 + (n & 15) * 32 + (c & 31)] = f2bf(y);
}

extern "C" void kernel_launch(void* const* d_in, const int* in_sizes, int n_in,
                              void* d_out, int out_size, void* d_ws, size_t ws_size,
                              hipStream_t stream) {
    const int* cfg_adj = (const int*)d_in[0];
    const int* cfg_nodes = (const int*)d_in[1];
    const int* cfg_len = (const int*)d_in[2];
    const float* emb = (const float*)d_in[3];
    const float* W = (const float*)d_in[4];
    const float* a_src = (const float*)d_in[5];
    const float* a_dst = (const float*)d_in[6];
    const float* ln_scale = (const float*)d_in[7];
    const float* ln_bias = (const float*)d_in[8];
    float* out = (float*)d_out;
    float* ws = (float*)d_ws;

    float* h = ws;
    float* hp = h + (size_t)B * N * D;
    float* srcv = hp + (size_t)B * H * N * DH;
    float* dstv = srcv + (size_t)B * H * N;
    unsigned short* h_sw = (unsigned short*)(dstv + (size_t)B * H * N);
    unsigned short* WhT = h_sw + (size_t)B * N * D;
    unsigned short* WT_sw = WhT + (size_t)B * H * DH * N;
    unsigned short* emb_bf = WT_sw + (size_t)NLAYERS * H * DH * D;
    unsigned long long* pack = (unsigned long long*)(emb_bf + (size_t)V * D);

    k_pre1<<<PRE1_GRID, 256, 0, stream>>>(cfg_adj, W, cfg_len, emb, pack, WT_sw,
                                          emb_bf, out + (size_t)B * N * D);
    k_nodefeat<<<B * N / 8, 256, 0, stream>>>(cfg_nodes, emb_bf, h, h_sw);
    for (int l = 0; l < NLAYERS; ++l) {
        k_wh<<<dim3(B * 64, H), 256, 0, stream>>>(
            h_sw, WT_sw + (size_t)l * H * 8 * 2048,
            a_src + (size_t)l * H * DH, a_dst + (size_t)l * H * DH,
            WhT, srcv, dstv);
        k_attn<<<B * H * 64, 256, 0, stream>>>(pack, srcv, dstv, WhT, hp);
        k_ln<<<B * N, 256, 0, stream>>>(h, hp, ln_scale, ln_bias,
                                        (l == NLAYERS - 1) ? out : h, h_sw,
                                        l, l < NLAYERS - 1 ? 1 : 0);
    }
}

// Round 13
// 196.336 us; speedup vs baseline: 1.3151x; 1.0313x over previous
//
#include <hip/hip_runtime.h>
#include <math.h>

#define B 8
#define N 1024
#define L 16
#define D 256
#define H 4
#define DH 64
#define NLAYERS 2
#define V 32000

typedef __attribute__((ext_vector_type(8))) short short8;
typedef __attribute__((ext_vector_type(4))) float f32x4;

union U8 { uint4 u; short8 s; };

__device__ inline unsigned short f2bf(float x) {
    unsigned u = __float_as_uint(x);
    u = (u + 0x7fff + ((u >> 16) & 1)) >> 16;  // RNE
    return (unsigned short)u;
}
__device__ inline float bf2f(unsigned short x) {
    return __uint_as_float(((unsigned)x) << 16);
}

// -------- layouts --------
// h_sw  [b][n>>4][d>>5][n&15][d&31]  bf16  residual stream (A of k_wh)
// WT_sw [lh][d>>5][dh][d&31]         bf16  (B of k_wh)
// WhT   [bh][m>>5][dh][m&31]         bf16  (B of k_attn)
// hp_bf [bh][n][dh]                  bf16  attn output
// pack  [b][n][m/64]                 u64 adjacency (+self-loop)

#define PACK_BLK 2048
#define WT_BLK   (NLAYERS * H * 4)   // 32
#define FEAT_BLK 2048                // B*N/4
#define PRE1_GRID (PACK_BLK + WT_BLK + FEAT_BLK + 1)

// ---- pre1: packadj + WT transpose + node_feat gather + len (all independent) ----
__global__ __launch_bounds__(256) void k_pre1(const int* __restrict__ adj,
                                              const float* __restrict__ W,
                                              const int* __restrict__ len,
                                              const float* __restrict__ emb,
                                              const int* __restrict__ nodes,
                                              unsigned long long* __restrict__ pack,
                                              unsigned short* __restrict__ WT_sw,
                                              unsigned short* __restrict__ h_sw,
                                              float* __restrict__ out_len) {
    int bid = blockIdx.x;
    int t = threadIdx.x;
    if (bid < PACK_BLK) {
        int row = bid * 4 + (t >> 6);  // bn
        int lane = t & 63;
        int n = row & (N - 1);
        const int* arow = adj + (long)row * N;
        unsigned long long* prow = pack + (size_t)row * 16;
        int g16 = lane & 15;
#pragma unroll
        for (int it = 0; it < 4; ++it) {
            int m0 = it * 256 + lane * 4;
            int4 a = *(const int4*)(arow + m0);
            unsigned nib = (unsigned)((a.x != 0) || (m0 == n))
                         | ((unsigned)((a.y != 0) || (m0 + 1 == n)) << 1)
                         | ((unsigned)((a.z != 0) || (m0 + 2 == n)) << 2)
                         | ((unsigned)((a.w != 0) || (m0 + 3 == n)) << 3);
            unsigned long long v = (unsigned long long)nib << (g16 * 4);
            v |= __shfl_xor(v, 1, 64);
            v |= __shfl_xor(v, 2, 64);
            v |= __shfl_xor(v, 4, 64);
            v |= __shfl_xor(v, 8, 64);
            if (g16 == 0) prow[it * 4 + (lane >> 4)] = v;
        }
    } else if (bid < PACK_BLK + WT_BLK) {
        int idx = bid - PACK_BLK;
        int lh = idx >> 2, q = idx & 3;
        const float* Wl = W + (size_t)lh * D * DH;
        int dh = t & 63;
        int d0 = q * 64 + (t >> 6) * 16;
#pragma unroll
        for (int i = 0; i < 16; ++i) {
            int d = d0 + i;
            WT_sw[(((size_t)lh * 8 + (d >> 5)) * 64 + dh) * 32 + (d & 31)] = f2bf(Wl[(size_t)d * DH + dh]);
        }
    } else if (bid < PACK_BLK + WT_BLK + FEAT_BLK) {
        // node_feat: mean of fp32 token embeddings -> h_sw bf16 (swizzled)
        int row = (bid - PACK_BLK - WT_BLK) * 4 + (t >> 6);  // bn
        int lane = t & 63;
        int d4 = lane * 4;
        const int* np = nodes + row * L;
        float4 s = make_float4(0.f, 0.f, 0.f, 0.f);
#pragma unroll
        for (int l = 0; l < L; ++l) {
            float4 v = *(const float4*)&emb[(size_t)np[l] * D + d4];
            s.x += v.x; s.y += v.y; s.z += v.z; s.w += v.w;
        }
        s.x *= (1.0f / L); s.y *= (1.0f / L); s.z *= (1.0f / L); s.w *= (1.0f / L);
        int b = row >> 10, n = row & 1023;
        ushort4 o;
        o.x = f2bf(s.x); o.y = f2bf(s.y); o.z = f2bf(s.z); o.w = f2bf(s.w);
        *(ushort4*)&h_sw[(((size_t)b * 64 + (n >> 4)) * 8 + (d4 >> 5)) * 512 + (n & 15) * 32 + (d4 & 31)] = o;
    } else {
        if (t < B) out_len[t] = (float)len[t];
    }
}

// ---- k_wh: WhT = (h @ W)^T via MFMA; epilogue computes srcv/dstv = Wh·a ----
__global__ __launch_bounds__(256) void k_wh(const unsigned short* __restrict__ h_sw,
                                            const unsigned short* __restrict__ WT_l,
                                            const float* __restrict__ asrc_l,
                                            const float* __restrict__ adst_l,
                                            unsigned short* __restrict__ WhT,
                                            float* __restrict__ srcv,
                                            float* __restrict__ dstv) {
    __shared__ float red[4][16][68];
    int bt = blockIdx.x;   // b*64 + nt
    int hh = blockIdx.y;
    int b = bt >> 6;
    int nt = bt & 63;
    int n0 = nt * 16;
    int tid = threadIdx.x;
    int w = tid >> 6, lane = tid & 63;
    int rowLane = lane & 15, quad = lane >> 4;
    int bh = b * H + hh;
    const unsigned short* abase = h_sw + (((size_t)b * 64 + nt) * 8) * 512 + rowLane * 32 + quad * 8;
    const unsigned short* bbase = WT_l + ((size_t)hh * 8) * 2048 + rowLane * 32 + quad * 8;
    f32x4 acc[4] = {};
#pragma unroll
    for (int kk = 0; kk < 2; ++kk) {
        int kc = w * 2 + kk;
        short8 af = *(const short8*)(abase + kc * 512);
#pragma unroll
        for (int c = 0; c < 4; ++c) {
            short8 bf = *(const short8*)(bbase + kc * 2048 + c * 512);
            acc[c] = __builtin_amdgcn_mfma_f32_16x16x32_bf16(af, bf, acc[c], 0, 0, 0);
        }
    }
#pragma unroll
    for (int c = 0; c < 4; ++c)
#pragma unroll
        for (int r = 0; r < 4; ++r)
            red[w][quad * 4 + r][c * 16 + rowLane] = acc[c][r];
    __syncthreads();
    int dh = tid >> 2, j4 = tid & 3;
    float v[4];
#pragma unroll
    for (int i = 0; i < 4; ++i)
        v[i] = red[0][j4 * 4 + i][dh] + red[1][j4 * 4 + i][dh] + red[2][j4 * 4 + i][dh] + red[3][j4 * 4 + i][dh];
    ushort4 o;
    o.x = f2bf(v[0]); o.y = f2bf(v[1]); o.z = f2bf(v[2]); o.w = f2bf(v[3]);
    *(ushort4*)&WhT[(((size_t)bh * 32 + (n0 >> 5)) * 64 + dh) * 32 + (n0 & 31) + j4 * 4] = o;
    // ---- srcv/dstv = Wh·a (reuse red as ps/pd) ----
    float as = asrc_l[hh * DH + dh];
    float ad = adst_l[hh * DH + dh];
    float* ps = &red[0][0][0];
    float* pd = ps + 16 * 68;
    __syncthreads();   // red reads done
#pragma unroll
    for (int i = 0; i < 4; ++i) {
        ps[(j4 * 4 + i) * 68 + dh] = v[i] * as;
        pd[(j4 * 4 + i) * 68 + dh] = v[i] * ad;
    }
    __syncthreads();
    int nl = tid >> 4, g = tid & 15;
    float4 s4 = *(float4*)&ps[nl * 68 + g * 4];
    float4 t4 = *(float4*)&pd[nl * 68 + g * 4];
    float s1 = s4.x + s4.y + s4.z + s4.w;
    float d1 = t4.x + t4.y + t4.z + t4.w;
#pragma unroll
    for (int off = 8; off; off >>= 1) {
        s1 += __shfl_xor(s1, off, 16);
        d1 += __shfl_xor(d1, off, 16);
    }
    if (g == 0) {
        srcv[bh * N + n0 + nl] = s1;
        dstv[bh * N + n0 + nl] = d1;
    }
}

// ---- k_attn: alpha@Wh, deferred normalization, local shift mx=lrelu(src).
// Block = (bh, 16-row n-tile). Wave w owns m-slab [w*256,(w+1)*256). ----
__global__ __launch_bounds__(256) void k_attn(const unsigned long long* __restrict__ pack,
                                              const float* __restrict__ srcv,
                                              const float* __restrict__ dstv,
                                              const unsigned short* __restrict__ WhT,
                                              unsigned short* __restrict__ hp_bf) {
    __shared__ float red[4][16][68];     // first 1024 floats alias dsts[4][256]
    __shared__ float ssum[4][16];
    float* dsts = &red[0][0][0];

    int tid = threadIdx.x;
    int bt = blockIdx.x;
    int bh = bt >> 6;
    int n0 = (bt & 63) * 16;
    int b = bh >> 2;
    int w = tid >> 6, lane = tid & 63;
    int rowLane = lane & 15, quad = lane >> 4;
    int n = n0 + rowLane;

    {
        float4 v = *(const float4*)(dstv + bh * N + w * 256 + lane * 4);
        *(float4*)(dsts + w * 256 + lane * 4) = v;
    }
    const uint4* pbp = (const uint4*)((const unsigned char*)(pack + ((size_t)(b * N + n)) * 16) + w * 32);
    uint4 pbv0 = pbp[0];
    uint4 pbv1 = pbp[1];
    float src = srcv[bh * N + n];
    float mx = src > 0.f ? src : 0.2f * src;   // local stable shift (h' invariant)

    unsigned words[8] = {pbv0.x, pbv0.y, pbv0.z, pbv0.w, pbv1.x, pbv1.y, pbv1.z, pbv1.w};
    const unsigned short* wbase = WhT + ((size_t)bh * 32) * 2048 + rowLane * 32 + quad * 8;
    f32x4 acc[4] = {};
    float sum0 = 0.f, sum1 = 0.f;
#pragma unroll
    for (int t2 = 0; t2 < 8; ++t2) {
        unsigned bits = (words[t2] >> (quad * 8)) & 0xffu;
        float4 d0 = *(const float4*)(dsts + w * 256 + t2 * 32 + quad * 8);
        float4 d1 = *(const float4*)(dsts + w * 256 + t2 * 32 + quad * 8 + 4);
        float dd[8] = {d0.x, d0.y, d0.z, d0.w, d1.x, d1.y, d1.z, d1.w};
        unsigned pk[4];
#pragma unroll
        for (int j2 = 0; j2 < 4; ++j2) {
            float ea = src + dd[2 * j2];
            float eb = src + dd[2 * j2 + 1];
            ea = ea > 0.f ? ea : 0.2f * ea;
            eb = eb > 0.f ? eb : 0.2f * eb;
            float pa = ((bits >> (2 * j2)) & 1) ? __expf(ea - mx) : 0.f;
            float pb = ((bits >> (2 * j2 + 1)) & 1) ? __expf(eb - mx) : 0.f;
            sum0 += pa; sum1 += pb;
            pk[j2] = (__float_as_uint(pb) & 0xffff0000u) | (__float_as_uint(pa) >> 16);
        }
        U8 u; u.u = make_uint4(pk[0], pk[1], pk[2], pk[3]);
        short8 af = u.s;
        const unsigned short* tb = wbase + (size_t)(w * 8 + t2) * 2048;
        acc[0] = __builtin_amdgcn_mfma_f32_16x16x32_bf16(af, *(const short8*)(tb + 0 * 512), acc[0], 0, 0, 0);
        acc[1] = __builtin_amdgcn_mfma_f32_16x16x32_bf16(af, *(const short8*)(tb + 1 * 512), acc[1], 0, 0, 0);
        acc[2] = __builtin_amdgcn_mfma_f32_16x16x32_bf16(af, *(const short8*)(tb + 2 * 512), acc[2], 0, 0, 0);
        acc[3] = __builtin_amdgcn_mfma_f32_16x16x32_bf16(af, *(const short8*)(tb + 3 * 512), acc[3], 0, 0, 0);
    }
    float sum = sum0 + sum1;
    sum += __shfl_xor(sum, 16, 64);
    sum += __shfl_xor(sum, 32, 64);
    if (quad == 0) ssum[w][rowLane] = sum;
    __syncthreads();
#pragma unroll
    for (int c = 0; c < 4; ++c)
#pragma unroll
        for (int r = 0; r < 4; ++r)
            red[w][quad * 4 + r][c * 16 + rowLane] = acc[c][r];
    __syncthreads();
    int row = tid >> 4, col4 = (tid & 15) * 4;
    float4 s = make_float4(0.f, 0.f, 0.f, 0.f);
#pragma unroll
    for (int ww = 0; ww < 4; ++ww) {
        float4 v = *(const float4*)&red[ww][row][col4];
        s.x += v.x; s.y += v.y; s.z += v.z; s.w += v.w;
    }
    float invr = 1.0f / (ssum[0][row] + ssum[1][row] + ssum[2][row] + ssum[3][row]);
    ushort4 o;
    o.x = f2bf(s.x * invr); o.y = f2bf(s.y * invr);
    o.z = f2bf(s.z * invr); o.w = f2bf(s.w * invr);
    *(ushort4*)&hp_bf[((size_t)bh * N + n0 + row) * DH + col4] = o;
}

// ---- k_ln: LN(h_sw + hp_bf); writes h_sw (mid) or out fp32 (final) ----
__global__ __launch_bounds__(256) void k_ln(const unsigned short* __restrict__ h_sw_in,
                                            const unsigned short* __restrict__ hp_bf,
                                            const float* __restrict__ scale,
                                            const float* __restrict__ bias,
                                            float* __restrict__ out,
                                            unsigned short* __restrict__ h_sw_out,
                                            int layer, int is_final) {
    __shared__ float red[8];
    int bn = blockIdx.x;
    int b = bn >> 10, n = bn & 1023;
    int c = threadIdx.x;
    int hh = c >> 6, k = c & 63;
    size_t swidx = (((size_t)b * 64 + (n >> 4)) * 8 + (c >> 5)) * 512 + (n & 15) * 32 + (c & 31);
    float x = bf2f(h_sw_in[swidx]) + bf2f(hp_bf[((size_t)(b * H + hh) * N + n) * DH + k]);
    float s = x, s2 = x * x;
#pragma unroll
    for (int off = 32; off; off >>= 1) {
        s += __shfl_xor(s, off, 64);
        s2 += __shfl_xor(s2, off, 64);
    }
    int w = c >> 6, lane = c & 63;
    if (lane == 0) { red[w] = s; red[4 + w] = s2; }
    __syncthreads();
    s = red[0] + red[1] + red[2] + red[3];
    s2 = red[4] + red[5] + red[6] + red[7];
    float mu = s * (1.0f / D);
    float var = s2 * (1.0f / D) - mu * mu;
    float r = rsqrtf(var + 1e-5f);
    float y = (x - mu) * r * scale[layer * D + c] + bias[layer * D + c];
    if (is_final) out[(size_t)bn * D + c] = y;
    else h_sw_out[swidx] = f2bf(y);
}

extern "C" void kernel_launch(void* const* d_in, const int* in_sizes, int n_in,
                              void* d_out, int out_size, void* d_ws, size_t ws_size,
                              hipStream_t stream) {
    const int* cfg_adj = (const int*)d_in[0];
    const int* cfg_nodes = (const int*)d_in[1];
    const int* cfg_len = (const int*)d_in[2];
    const float* emb = (const float*)d_in[3];
    const float* W = (const float*)d_in[4];
    const float* a_src = (const float*)d_in[5];
    const float* a_dst = (const float*)d_in[6];
    const float* ln_scale = (const float*)d_in[7];
    const float* ln_bias = (const float*)d_in[8];
    float* out = (float*)d_out;
    float* ws = (float*)d_ws;

    float* srcv = ws;
    float* dstv = srcv + (size_t)B * H * N;
    unsigned short* h_sw = (unsigned short*)(dstv + (size_t)B * H * N);
    unsigned short* WhT = h_sw + (size_t)B * N * D;
    unsigned short* WT_sw = WhT + (size_t)B * H * DH * N;
    unsigned short* hp_bf = WT_sw + (size_t)NLAYERS * H * DH * D;
    unsigned long long* pack = (unsigned long long*)(hp_bf + (size_t)B * H * N * DH);

    k_pre1<<<PRE1_GRID, 256, 0, stream>>>(cfg_adj, W, cfg_len, emb, cfg_nodes,
                                          pack, WT_sw, h_sw, out + (size_t)B * N * D);
    for (int l = 0; l < NLAYERS; ++l) {
        k_wh<<<dim3(B * 64, H), 256, 0, stream>>>(
            h_sw, WT_sw + (size_t)l * H * 8 * 2048,
            a_src + (size_t)l * H * DH, a_dst + (size_t)l * H * DH,
            WhT, srcv, dstv);
        k_attn<<<B * H * 64, 256, 0, stream>>>(pack, srcv, dstv, WhT, hp_bf);
        k_ln<<<B * N, 256, 0, stream>>>(h_sw, hp_bf, ln_scale, ln_bias,
                                        out, h_sw, l, l == NLAYERS - 1 ? 1 : 0);
    }
}